// Round 7
// baseline (33381.860 us; speedup 1.0000x reference)
//
#include <hip/hip_runtime.h>
#include <stdint.h>

typedef unsigned short u16;
typedef unsigned long long u64;
typedef __bf16 bf16x8 __attribute__((ext_vector_type(8)));
typedef float f32x4 __attribute__((ext_vector_type(4)));

#define S_LEN 288
#define T_LEN 144
#define HID   512
#define BATCH 2048
#define NBLK  512
#define THREADS 512
#define HBUF  ((size_t)BATCH * HID)

// LDS arena (u16 elems): two staged A tiles (32 rows) + h scratch
// A tile: 16 chunks, pitch 1032 elems (32 rows x 32 + 8 pad)
#define APITCH 1032
#define ATILE  (16*APITCH)          // 16512 elems
#define SCROFF (2*ATILE)
#define ARENA_ELEMS (2*ATILE + 32*68)   // 70400 B -> 2 blocks/CU

__device__ __forceinline__ u16 f2bf(float f){
  unsigned u = __builtin_bit_cast(unsigned, f);
  u = u + 0x7fffu + ((u >> 16) & 1u);
  return (u16)(u >> 16);
}
__device__ __forceinline__ float sigf(float x){ return 1.0f/(1.0f + __expf(-x)); }
__device__ __forceinline__ float tanh_f(float x){ return 1.0f - 2.0f/(1.0f + __expf(2.0f*x)); }

// agent-scope (sc1): bypass per-XCD L2, device-coherent (replay-proven R2/R4/R5)
__device__ __forceinline__ u64 aload64(const u16* p){
  return __hip_atomic_load((const u64*)p, __ATOMIC_RELAXED, __HIP_MEMORY_SCOPE_AGENT);
}
__device__ __forceinline__ float aloadf(const float* p){
  return __hip_atomic_load(p, __ATOMIC_RELAXED, __HIP_MEMORY_SCOPE_AGENT);
}
__device__ __forceinline__ void astore64(void* p, u64 v){
  __hip_atomic_store((u64*)p, v, __ATOMIC_RELAXED, __HIP_MEMORY_SCOPE_AGENT);
}
__device__ __forceinline__ void astoref(float* p, float v){
  __hip_atomic_store(p, v, __ATOMIC_RELAXED, __HIP_MEMORY_SCOPE_AGENT);
}

struct Params {
  const float* x;
  const u16 *We0, *We1i, *We1h, *Wd0, *Wd1i, *Wd1h;
  const float *be0, *be1, *bd0, *bd1, *wxe, *wxd, *fcW, *fcbp;
  u16 *h0buf, *h1buf;
  float* preds;
  unsigned* gcnt;
  float* out;
};

// ---------------- prep kernels ----------------
// orig row = gate*512 + hu  ->  new row = (hu>>3)*32 + gate*8 + (hu&7)
__global__ void k_reorder_w(const float* __restrict__ src, u16* __restrict__ dst){
  int idx  = blockIdx.x * 256 + threadIdx.x;
  int k    = idx & (HID-1);
  int orig = idx >> 9;
  int gate = orig >> 9, hu = orig & (HID-1);
  int nr   = ((hu >> 3) << 5) + (gate << 3) + (hu & 7);
  dst[(size_t)nr * HID + k] = f2bf(src[idx]);
}

__global__ void k_prep_small(const float* __restrict__ bih, const float* __restrict__ bhh,
                             float* __restrict__ bdst,
                             const float* __restrict__ wcol, float* __restrict__ wdst){
  int orig = blockIdx.x * 256 + threadIdx.x;
  int gate = orig >> 9, hu = orig & (HID-1);
  int nr   = ((hu >> 3) << 5) + (gate << 3) + (hu & 7);
  bdst[nr] = bih[orig] + bhh[orig];
  if (wcol) wdst[nr] = wcol[orig];
}

// ---------------- m-group barrier (8 blocks, own cacheline, R2-proven shape) ----------------
__device__ __forceinline__ void gbar(unsigned* cnt, unsigned& epoch){
  __syncthreads();
  ++epoch;
  if (threadIdx.x == 0){
    __hip_atomic_fetch_add(cnt, 1u, __ATOMIC_RELEASE, __HIP_MEMORY_SCOPE_AGENT);
    const unsigned tgt = epoch * 8u;
    while (__hip_atomic_load(cnt, __ATOMIC_RELAXED, __HIP_MEMORY_SCOPE_AGENT) < tgt)
      __builtin_amdgcn_s_sleep(1);
  }
  __syncthreads();
}

// ---------------- A-tile staging: one burst of sc1 loads -> LDS ----------------
// tile = 32 rows x 512 cols (u16) = 4096 u64 units = 512 thr x 8.
// unit: r = 4i + (tid>>7), c = (tid>>3)&15, q8 = tid&7
__device__ __forceinline__ void stage1(const u16* __restrict__ Ag, u16* lA, int tid){
  const int rb = tid >> 7, c = (tid >> 3) & 15, q8 = tid & 7;
  const int s = q8 >> 1, hh = (q8 & 1) * 4;
  const size_t gb = (size_t)c*32 + q8*4;
  u64 v[8];
  #pragma unroll
  for (int i = 0; i < 8; ++i)
    v[i] = aload64(Ag + (size_t)(4*i + rb)*HID + gb);
  #pragma unroll
  for (int i = 0; i < 8; ++i){
    const int r = 4*i + rb;
    *(u64*)&lA[c*APITCH + r*32 + ((s ^ ((r>>1)&3))<<3) + hh] = v[i];
  }
}

// stage two tiles, single latency exposure (all 16 loads in flight together)
__device__ __forceinline__ void stage2(const u16* __restrict__ A0, const u16* __restrict__ A1,
                                       u16* lA0, u16* lA1, int tid){
  const int rb = tid >> 7, c = (tid >> 3) & 15, q8 = tid & 7;
  const int s = q8 >> 1, hh = (q8 & 1) * 4;
  const size_t gb = (size_t)c*32 + q8*4;
  u64 v0[8], v1[8];
  #pragma unroll
  for (int i = 0; i < 8; ++i) v0[i] = aload64(A0 + (size_t)(4*i + rb)*HID + gb);
  #pragma unroll
  for (int i = 0; i < 8; ++i) v1[i] = aload64(A1 + (size_t)(4*i + rb)*HID + gb);
  #pragma unroll
  for (int i = 0; i < 8; ++i){
    const int r = 4*i + rb;
    *(u64*)&lA0[c*APITCH + r*32 + ((s ^ ((r>>1)&3))<<3) + hh] = v0[i];
  }
  #pragma unroll
  for (int i = 0; i < 8; ++i){
    const int r = 4*i + rb;
    *(u64*)&lA1[c*APITCH + r*32 + ((s ^ ((r>>1)&3))<<3) + hh] = v1[i];
  }
}

// ---------------- K=512 GEMM from staged LDS A, B streamed w/ depth-3 prefetch ----------------
// wave tile: 32m x 32n (mf 2 x nf 2)
template<bool DUAL>
__device__ __forceinline__ void gemm_lds(
    const u16* lA, const u16* __restrict__ Bg, const u16* __restrict__ B2g,
    f32x4 (&acc)[2][2], f32x4 (&acc2)[2][2],
    const int (&aloff)[2], const int (&boff)[2])
{
  int4 bq[3][2], b2q[3][2];
  #pragma unroll
  for (int st = 0; st < 3; ++st)
    #pragma unroll
    for (int nf = 0; nf < 2; ++nf){
      bq[st][nf] = *(const int4*)(Bg + boff[nf] + st*32);
      if (DUAL) b2q[st][nf] = *(const int4*)(B2g + boff[nf] + st*32);
    }
  #pragma unroll
  for (int c = 0; c < 16; ++c){
    bf16x8 af[2];
    #pragma unroll
    for (int mf = 0; mf < 2; ++mf)
      af[mf] = *(const bf16x8*)&lA[c*APITCH + aloff[mf]];
    const int st = c % 3;
    #pragma unroll
    for (int mf = 0; mf < 2; ++mf)
      #pragma unroll
      for (int nf = 0; nf < 2; ++nf){
        acc[mf][nf] = __builtin_amdgcn_mfma_f32_16x16x32_bf16(
            af[mf], __builtin_bit_cast(bf16x8, bq[st][nf]), acc[mf][nf], 0, 0, 0);
        if (DUAL)
          acc2[mf][nf] = __builtin_amdgcn_mfma_f32_16x16x32_bf16(
              af[mf], __builtin_bit_cast(bf16x8, b2q[st][nf]), acc2[mf][nf], 0, 0, 0);
      }
    if (c < 13){
      #pragma unroll
      for (int nf = 0; nf < 2; ++nf){
        bq[st][nf] = *(const int4*)(Bg + boff[nf] + (c+3)*32);
        if (DUAL) b2q[st][nf] = *(const int4*)(B2g + boff[nf] + (c+3)*32);
      }
    }
  }
}

// ---------------- LSTM cell epilogue (R4/R5-proven gate mapping) ----------------
template<bool X0, bool PRED>
__device__ __forceinline__ void cell_epi(
    f32x4 (&acc)[2][2], float* cst, const float* bv, const float* wxv,
    const float* xin, u16* scr,
    int wave, int quad, int l15, int m0,
    float fcWv, float* predrow)
{
  const int hilane = l15 >> 3, hu7 = l15 & 7;
  #pragma unroll
  for (int mf = 0; mf < 2; ++mf){
    #pragma unroll
    for (int r = 0; r < 4; ++r){
      const float a0 = acc[mf][0][r], a1 = acc[mf][1][r];
      const float p0 = __shfl_xor(a0, 8), p1 = __shfl_xor(a1, 8);
      float gi = (hilane ? p0 : a0) + bv[0];
      float gf = (hilane ? a0 : p0) + bv[1];
      float gg = (hilane ? p1 : a1) + bv[2];
      float go = (hilane ? a1 : p1) + bv[3];
      if (X0){
        const float xt = xin[mf*4 + r];
        gi += xt*wxv[0]; gf += xt*wxv[1]; gg += xt*wxv[2]; go += xt*wxv[3];
      }
      const float c = sigf(gf)*cst[mf*4+r] + sigf(gi)*tanh_f(gg);
      cst[mf*4+r] = c;
      const float h = sigf(go)*tanh_f(c);
      if (!hilane) scr[(mf*16 + quad*4 + r)*68 + wave*8 + hu7] = f2bf(h);
      if (PRED){
        float v = hilane ? 0.f : h*fcWv;
        v += __shfl_xor(v, 1); v += __shfl_xor(v, 2);
        v += __shfl_xor(v, 4); v += __shfl_xor(v, 8);
        if (l15 == 0) atomicAdd(&predrow[m0 + mf*16 + quad*4 + r], v);
      }
    }
  }
}

// drain scratch (32 rows x 64 cols, pitch 68) -> global h (sc1, 16B/thread, 256 thr)
// R6 BUG FIXED: one u64 = 4 u16 cols; with q stride 8 cols we must copy TWO u64s
// per thread (256 thr x 8 cols = 2048 u16 = full tile). R6 copied only half.
__device__ __forceinline__ void drain_h(const u16* scr, u16* hdst, int m0, int col0, int tid){
  __syncthreads();
  if (tid < 256){
    const int row = tid >> 3, q = tid & 7;
    const u64* s = (const u64*)(scr + row*68 + q*8);   // byte off row*136 (=17*8) + q*16: 8B-aligned
    const u64 lo = s[0], hi = s[1];
    u64* d = (u64*)(hdst + (size_t)(m0+row)*HID + col0 + q*8);
    astore64(d, lo);
    astore64(d+1, hi);
  }
  __syncthreads();
}

// ---------------- persistent main kernel ----------------
__global__ __launch_bounds__(THREADS, 4) void lstm_main(Params P){
  const int tid   = threadIdx.x;
  const int bx    = blockIdx.x;
  const int n_blk = bx & 7;            // same n-slice per XCD (L2-residency heuristic)
  const int m_blk = bx >> 3;           // 0..63; m-group = 8 consecutive bx
  const int m0 = m_blk * 32;
  const int wave = tid >> 6, lane = tid & 63;
  const int l15 = lane & 15, quad = lane >> 4;
  const int hu7 = l15 & 7;
  const int hu = n_blk*64 + wave*8 + hu7;
  const int col0 = n_blk*64;

  __shared__ u16 arena[ARENA_ELEMS];   // 70.4 KB -> 2 blocks/CU
  u16* lA0 = arena;
  u16* lA1 = arena + ATILE;
  u16* scr = arena + SCROFF;

  unsigned* cnt = P.gcnt + m_blk*32;   // 128B-spaced per-group line

  int aloff[2], boff[2];
  #pragma unroll
  for (int mf = 0; mf < 2; ++mf){
    const int r = mf*16 + l15;
    aloff[mf] = r*32 + ((quad ^ ((r>>1)&3))<<3);
  }
  #pragma unroll
  for (int nf = 0; nf < 2; ++nf)
    boff[nf] = (wave*32 + nf*16 + l15)*HID + quad*8;

  float c0s[8], c1s[8];
  #pragma unroll
  for (int i = 0; i < 8; ++i){ c0s[i] = 0.f; c1s[i] = 0.f; }

  float be0v[4], be1v[4], bd0v[4], bd1v[4], wxev[4], wxdv[4];
  #pragma unroll
  for (int g = 0; g < 4; ++g){
    const int col = n_blk*256 + wave*32 + g*8 + hu7;
    be0v[g] = P.be0[col]; be1v[g] = P.be1[col];
    bd0v[g] = P.bd0[col]; bd1v[g] = P.bd1[col];
    wxev[g] = P.wxe[col]; wxdv[g] = P.wxd[col];
  }
  const float fcWv = P.fcW[hu];
  const float fcb  = P.fcbp[0];

  const size_t nb = (size_t)(n_blk*256) * HID;
  const u16* We0b  = P.We0  + nb;
  const u16* We1ib = P.We1i + nb;
  const u16* We1hb = P.We1h + nb;
  const u16* Wd0b  = P.Wd0  + nb;
  const u16* Wd1ib = P.Wd1i + nb;
  const u16* Wd1hb = P.Wd1h + nb;
  const size_t mb = (size_t)m0 * HID;
  u16* h0b[2] = { P.h0buf, P.h0buf + HBUF };
  u16* h1b[2] = { P.h1buf, P.h1buf + HBUF };

  unsigned epoch = 0;

  // ===== encoder: phase p runs layer0(t=p) and layer1(t=p-1) =====
  for (int p = 0; p <= S_LEN; ++p){
    stage2(h0b[p & 1] + mb, h1b[(p+1) & 1] + mb, lA0, lA1, tid);
    __syncthreads();

    f32x4 acc0[2][2], acc1[2][2];
    #pragma unroll
    for (int i = 0; i < 2; ++i)
      #pragma unroll
      for (int j = 0; j < 2; ++j){ acc0[i][j] = f32x4{0.f,0.f,0.f,0.f}; acc1[i][j] = f32x4{0.f,0.f,0.f,0.f}; }

    gemm_lds<true >(lA0, We0b, We1ib, acc0, acc1, aloff, boff);
    gemm_lds<false>(lA1, We1hb, We1hb, acc1, acc1, aloff, boff);

    if (p < S_LEN){
      float xin[8];
      #pragma unroll
      for (int mf = 0; mf < 2; ++mf)
        #pragma unroll
        for (int r = 0; r < 4; ++r)
          xin[mf*4+r] = P.x[(size_t)(m0 + mf*16 + quad*4 + r)*S_LEN + p];
      cell_epi<true,false>(acc0, c0s, be0v, wxev, xin, scr, wave, quad, l15, m0, 0.f, nullptr);
      drain_h(scr, h0b[(p+1) & 1], m0, col0, tid);
    }
    if (p >= 1){
      cell_epi<false,false>(acc1, c1s, be1v, nullptr, nullptr, scr, wave, quad, l15, m0, 0.f, nullptr);
      drain_h(scr, h1b[p & 1], m0, col0, tid);
    }
    gbar(cnt, epoch);
  }

  // ===== decoder: 2 phases per step (pred feedback) =====
  for (int t = 0; t < T_LEN; ++t){
    if (t > 0 && n_blk == 0 && tid < 32){
      const float pv = aloadf(&P.preds[((t+1) & 1)*BATCH + m0 + tid]);
      P.out[(size_t)(m0 + tid)*T_LEN + (t-1)] = pv + fcb;
    }
    { // phase A: dec layer0
      stage1(h0b[t & 1] + mb, lA0, tid);
      __syncthreads();
      f32x4 acc0[2][2];
      #pragma unroll
      for (int i = 0; i < 2; ++i)
        #pragma unroll
        for (int j = 0; j < 2; ++j) acc0[i][j] = f32x4{0.f,0.f,0.f,0.f};
      gemm_lds<false>(lA0, Wd0b, Wd0b, acc0, acc0, aloff, boff);
      float xin[8];
      #pragma unroll
      for (int mf = 0; mf < 2; ++mf)
        #pragma unroll
        for (int r = 0; r < 4; ++r){
          const int b = m0 + mf*16 + quad*4 + r;
          xin[mf*4+r] = (t == 0) ? P.x[(size_t)b*S_LEN + (S_LEN-1)]
                                 : (aloadf(&P.preds[((t+1) & 1)*BATCH + b]) + fcb);
        }
      cell_epi<true,false>(acc0, c0s, bd0v, wxdv, xin, scr, wave, quad, l15, m0, 0.f, nullptr);
      drain_h(scr, h0b[(t+1) & 1], m0, col0, tid);
    }
    gbar(cnt, epoch);
    // phase B: dec layer1 + pred reduce
    if (n_blk == 0 && tid < 32)
      astoref(&P.preds[((t+1) & 1)*BATCH + m0 + tid], 0.f);   // recycle for step t+1
    {
      stage2(h0b[(t+1) & 1] + mb, h1b[t & 1] + mb, lA0, lA1, tid);
      __syncthreads();
      f32x4 acc1[2][2];
      #pragma unroll
      for (int i = 0; i < 2; ++i)
        #pragma unroll
        for (int j = 0; j < 2; ++j) acc1[i][j] = f32x4{0.f,0.f,0.f,0.f};
      gemm_lds<false>(lA0, Wd1ib, Wd1ib, acc1, acc1, aloff, boff);
      gemm_lds<false>(lA1, Wd1hb, Wd1hb, acc1, acc1, aloff, boff);
      cell_epi<false,true>(acc1, c1s, bd1v, nullptr, nullptr, scr, wave, quad, l15, m0,
                           fcWv, P.preds + (t & 1)*BATCH);
      drain_h(scr, h1b[(t+1) & 1], m0, col0, tid);
    }
    gbar(cnt, epoch);
  }
  if (n_blk == 0 && tid < 32){
    const float pv = aloadf(&P.preds[((T_LEN-1) & 1)*BATCH + m0 + tid]);
    P.out[(size_t)(m0 + tid)*T_LEN + (T_LEN-1)] = pv + fcb;
  }
}

// ---------------- host launcher ----------------
extern "C" void kernel_launch(void* const* d_in, const int* in_sizes, int n_in,
                              void* d_out, int out_size, void* d_ws, size_t ws_size,
                              hipStream_t stream){
  const float* x     = (const float*)d_in[0];
  const float* eWih0 = (const float*)d_in[1];
  const float* eWhh0 = (const float*)d_in[2];
  const float* ebih0 = (const float*)d_in[3];
  const float* ebhh0 = (const float*)d_in[4];
  const float* eWih1 = (const float*)d_in[5];
  const float* eWhh1 = (const float*)d_in[6];
  const float* ebih1 = (const float*)d_in[7];
  const float* ebhh1 = (const float*)d_in[8];
  const float* dWih0 = (const float*)d_in[9];
  const float* dWhh0 = (const float*)d_in[10];
  const float* dbih0 = (const float*)d_in[11];
  const float* dbhh0 = (const float*)d_in[12];
  const float* dWih1 = (const float*)d_in[13];
  const float* dWhh1 = (const float*)d_in[14];
  const float* dbih1 = (const float*)d_in[15];
  const float* dbhh1 = (const float*)d_in[16];
  const float* fcW   = (const float*)d_in[17];
  const float* fcb   = (const float*)d_in[18];

  char* ws = (char*)d_ws;
  size_t off = 0;
  auto alloc = [&](size_t bytes)->char*{
    char* p = ws + off; off += (bytes + 255) & ~(size_t)255; return p;
  };
  u16* We0  = (u16*)alloc((size_t)2048*512*2);
  u16* We1i = (u16*)alloc((size_t)2048*512*2);
  u16* We1h = (u16*)alloc((size_t)2048*512*2);
  u16* Wd0  = (u16*)alloc((size_t)2048*512*2);
  u16* Wd1i = (u16*)alloc((size_t)2048*512*2);
  u16* Wd1h = (u16*)alloc((size_t)2048*512*2);
  char* zbase = ws + off;
  u16* h0buf = (u16*)alloc(2*HBUF*2);
  u16* h1buf = (u16*)alloc(2*HBUF*2);
  float* preds = (float*)alloc(2*BATCH*4);
  unsigned* gcnt = (unsigned*)alloc(64*32*4);
  size_t zbytes = (size_t)((ws + off) - zbase);
  float* be0 = (float*)alloc(2048*4);
  float* be1 = (float*)alloc(2048*4);
  float* bd0 = (float*)alloc(2048*4);
  float* bd1 = (float*)alloc(2048*4);
  float* wxe = (float*)alloc(2048*4);
  float* wxd = (float*)alloc(2048*4);

  hipMemsetAsync(zbase, 0, zbytes, stream);
  dim3 gw((2048*512)/256);
  k_reorder_w<<<gw,256,0,stream>>>(eWhh0, We0);
  k_reorder_w<<<gw,256,0,stream>>>(eWih1, We1i);
  k_reorder_w<<<gw,256,0,stream>>>(eWhh1, We1h);
  k_reorder_w<<<gw,256,0,stream>>>(dWhh0, Wd0);
  k_reorder_w<<<gw,256,0,stream>>>(dWih1, Wd1i);
  k_reorder_w<<<gw,256,0,stream>>>(dWhh1, Wd1h);
  k_prep_small<<<8,256,0,stream>>>(ebih0, ebhh0, be0, eWih0, wxe);
  k_prep_small<<<8,256,0,stream>>>(ebih1, ebhh1, be1, (const float*)nullptr, (float*)nullptr);
  k_prep_small<<<8,256,0,stream>>>(dbih0, dbhh0, bd0, dWih0, wxd);
  k_prep_small<<<8,256,0,stream>>>(dbih1, dbhh1, bd1, (const float*)nullptr, (float*)nullptr);

  Params P{ x, We0, We1i, We1h, Wd0, Wd1i, Wd1h,
            be0, be1, bd0, bd1, wxe, wxd, fcW, fcb,
            h0buf, h1buf, preds, gcnt, (float*)d_out };
  // 512 blocks x 512 threads = 2 blocks/CU: partner block hides sync + L3 latency
  lstm_main<<<dim3(NBLK), dim3(THREADS), 0, stream>>>(P);
}

// Round 8
// 22884.782 us; speedup vs baseline: 1.4587x; 1.4587x over previous
//
#include <hip/hip_runtime.h>
#include <stdint.h>

typedef unsigned short u16;
typedef unsigned long long u64;
typedef __bf16 bf16x8 __attribute__((ext_vector_type(8)));
typedef float f32x4 __attribute__((ext_vector_type(4)));

#define S_LEN 288
#define T_LEN 144
#define HID   512
#define BATCH 2048
#define NBLK  256
#define THREADS 512
#define HBUF  ((size_t)BATCH * HID)

// LDS arena (u16 elems): two staged A tiles (64 rows x 512 cols, chunk-major) + h scratch
// A tile: 16 chunks x (64 rows x 32 cols, row-major 64B rows, no pad) = 32768 elems (64KB)
#define ATILE  32768
#define SCROFF (2*ATILE)                 // 65536
#define ARENA_ELEMS (2*ATILE + 64*72)    // 70144 elems = 140288 B -> forces 1 block/CU

__device__ __forceinline__ u16 f2bf(float f){
  unsigned u = __builtin_bit_cast(unsigned, f);
  u = u + 0x7fffu + ((u >> 16) & 1u);
  return (u16)(u >> 16);
}
__device__ __forceinline__ float sigf(float x){ return 1.0f/(1.0f + __expf(-x)); }
__device__ __forceinline__ float tanh_f(float x){ return 1.0f - 2.0f/(1.0f + __expf(2.0f*x)); }

// agent-scope (sc1) — used ONLY for barrier counters and preds (tiny traffic)
__device__ __forceinline__ float aloadf(const float* p){
  return __hip_atomic_load(p, __ATOMIC_RELAXED, __HIP_MEMORY_SCOPE_AGENT);
}
__device__ __forceinline__ void astoref(float* p, float v){
  __hip_atomic_store(p, v, __ATOMIC_RELAXED, __HIP_MEMORY_SCOPE_AGENT);
}

// async global->LDS, 16B/lane, aux=1 (sc0: bypass L1, read XCD-local L2)
__device__ __forceinline__ void glds16(const u16* g, u16* l){
  __builtin_amdgcn_global_load_lds(
      (const __attribute__((address_space(1))) void*)g,
      (__attribute__((address_space(3))) void*)l, 16, 0, 1);
}

struct Params {
  const float* x;
  const u16 *We0, *We1i, *We1h, *Wd0, *Wd1i, *Wd1h;
  const float *be0, *be1, *bd0, *bd1, *wxe, *wxd, *fcW, *fcbp;
  u16 *h0buf, *h1buf;
  float* preds;
  unsigned* gcnt;
  unsigned* roster;
  float* out;
};

// ---------------- prep kernels ----------------
// orig row = gate*512 + hu  ->  new row = (hu>>3)*32 + gate*8 + (hu&7)
__global__ void k_reorder_w(const float* __restrict__ src, u16* __restrict__ dst){
  int idx  = blockIdx.x * 256 + threadIdx.x;
  int k    = idx & (HID-1);
  int orig = idx >> 9;
  int gate = orig >> 9, hu = orig & (HID-1);
  int nr   = ((hu >> 3) << 5) + (gate << 3) + (hu & 7);
  dst[(size_t)nr * HID + k] = f2bf(src[idx]);
}

__global__ void k_prep_small(const float* __restrict__ bih, const float* __restrict__ bhh,
                             float* __restrict__ bdst,
                             const float* __restrict__ wcol, float* __restrict__ wdst){
  int orig = blockIdx.x * 256 + threadIdx.x;
  int gate = orig >> 9, hu = orig & (HID-1);
  int nr   = ((hu >> 3) << 5) + (gate << 3) + (hu & 7);
  bdst[nr] = bih[orig] + bhh[orig];
  if (wcol) wdst[nr] = wcol[orig];
}

// ---------------- per-XCD barrier (32 blocks, own cacheline) ----------------
// __syncthreads drains vmcnt (h stores reach XCD L2 = coherence point) before arrival.
__device__ __forceinline__ void gbar(unsigned* cnt, unsigned& epoch){
  __syncthreads();
  ++epoch;
  if (threadIdx.x == 0){
    __hip_atomic_fetch_add(cnt, 1u, __ATOMIC_RELEASE, __HIP_MEMORY_SCOPE_AGENT);
    const unsigned tgt = epoch * 32u;
    while (__hip_atomic_load(cnt, __ATOMIC_RELAXED, __HIP_MEMORY_SCOPE_AGENT) < tgt)
      __builtin_amdgcn_s_sleep(1);
  }
  __syncthreads();
}

// ---------------- A-tile staging via lds-direct sc0 (XCD-local L2) ----------------
// LDS layout: chunk c at c*2048 elems; within, row r (0..63) at r*32, 64B rows.
// One glds16 issue = 1 wave x 16B = 1KB = chunk c, rows rq*16..rq*16+15.
// Per tile: 64 issues; per wave: 8 (idx = wave*8+j, c = idx>>2, rq = idx&3).
__device__ __forceinline__ void stage_tile(const u16* __restrict__ Ag, u16* lA,
                                           int wave, int lane){
  const int r_in = lane >> 2, qq = lane & 3;
  #pragma unroll
  for (int j = 0; j < 8; ++j){
    const int idx = wave*8 + j;
    const int c = idx >> 2, rq = idx & 3;
    const u16* g = Ag + (size_t)(rq*16 + r_in)*HID + c*32 + qq*8;
    glds16(g, lA + c*2048 + rq*512);
  }
}

// ---------------- K=512 GEMM: A from staged LDS, B streamed (plain loads, depth-3) ----
// wave tile: 64m x 32n (mf 4 x nf 2)
template<bool DUAL>
__device__ __forceinline__ void gemm_lds(
    const u16* lA, const u16* __restrict__ Bg, const u16* __restrict__ B2g,
    f32x4 (&acc)[4][2], f32x4 (&acc2)[4][2],
    const int (&aloff)[4], const int (&boff)[2])
{
  int4 bq[3][2], b2q[3][2];
  #pragma unroll
  for (int st = 0; st < 3; ++st)
    #pragma unroll
    for (int nf = 0; nf < 2; ++nf){
      bq[st][nf] = *(const int4*)(Bg + boff[nf] + st*32);
      if (DUAL) b2q[st][nf] = *(const int4*)(B2g + boff[nf] + st*32);
    }
  #pragma unroll
  for (int c = 0; c < 16; ++c){
    bf16x8 af[4];
    #pragma unroll
    for (int mf = 0; mf < 4; ++mf)
      af[mf] = *(const bf16x8*)&lA[c*2048 + aloff[mf]];
    const int st = c % 3;
    #pragma unroll
    for (int mf = 0; mf < 4; ++mf)
      #pragma unroll
      for (int nf = 0; nf < 2; ++nf){
        acc[mf][nf] = __builtin_amdgcn_mfma_f32_16x16x32_bf16(
            af[mf], __builtin_bit_cast(bf16x8, bq[st][nf]), acc[mf][nf], 0, 0, 0);
        if (DUAL)
          acc2[mf][nf] = __builtin_amdgcn_mfma_f32_16x16x32_bf16(
              af[mf], __builtin_bit_cast(bf16x8, b2q[st][nf]), acc2[mf][nf], 0, 0, 0);
      }
    if (c < 13){
      #pragma unroll
      for (int nf = 0; nf < 2; ++nf){
        bq[st][nf] = *(const int4*)(Bg + boff[nf] + (c+3)*32);
        if (DUAL) b2q[st][nf] = *(const int4*)(B2g + boff[nf] + (c+3)*32);
      }
    }
  }
}

// ---------------- LSTM cell epilogue (R4/R5-proven gate mapping) ----------------
// n-row (wave*32 + nf*16 + l15) -> gate nf*2+(l15>>3) of hu = n_sub*64 + wave*8 + (l15&7)
template<bool X0, bool PRED>
__device__ __forceinline__ void cell_epi(
    f32x4 (&acc)[4][2], float* cst, const float* bv, const float* wxv,
    const float* xin, u16* scr,
    int wave, int quad, int l15, int m0,
    float fcWv, float* predrow)
{
  const int hilane = l15 >> 3, hu7 = l15 & 7;
  #pragma unroll
  for (int mf = 0; mf < 4; ++mf){
    #pragma unroll
    for (int r = 0; r < 4; ++r){
      const float a0 = acc[mf][0][r], a1 = acc[mf][1][r];
      const float p0 = __shfl_xor(a0, 8), p1 = __shfl_xor(a1, 8);
      float gi = (hilane ? p0 : a0) + bv[0];
      float gf = (hilane ? a0 : p0) + bv[1];
      float gg = (hilane ? p1 : a1) + bv[2];
      float go = (hilane ? a1 : p1) + bv[3];
      if (X0){
        const float xt = xin[mf*4 + r];
        gi += xt*wxv[0]; gf += xt*wxv[1]; gg += xt*wxv[2]; go += xt*wxv[3];
      }
      const float c = sigf(gf)*cst[mf*4+r] + sigf(gi)*tanh_f(gg);
      cst[mf*4+r] = c;
      const float h = sigf(go)*tanh_f(c);
      if (!hilane) scr[(mf*16 + quad*4 + r)*72 + wave*8 + hu7] = f2bf(h);
      if (PRED){
        float v = hilane ? 0.f : h*fcWv;
        v += __shfl_xor(v, 1); v += __shfl_xor(v, 2);
        v += __shfl_xor(v, 4); v += __shfl_xor(v, 8);
        if (l15 == 0) atomicAdd(&predrow[m0 + mf*16 + quad*4 + r], v);
      }
    }
  }
}

// drain scratch (64 rows x 64 cols, pitch 72) -> global h (PLAIN stores -> XCD L2)
// 512 thr x 16B: row = tid>>3 (64), q = tid&7 (8 x 8 u16 = 64 cols)
__device__ __forceinline__ void drain_h(const u16* scr, u16* hdst, int m0, int col0, int tid){
  __syncthreads();
  const int row = tid >> 3, q = tid & 7;
  const int4 v = *(const int4*)(scr + row*72 + q*8);
  *(int4*)(hdst + (size_t)(m0+row)*HID + col0 + q*8) = v;
  __syncthreads();
}

// ---------------- persistent main kernel ----------------
__global__ __launch_bounds__(THREADS, 1) void lstm_main(Params P){
  const int tid = threadIdx.x;
  const int wave = tid >> 6, lane = tid & 63;
  const int l15 = lane & 15, quad = lane >> 4;
  const int hu7 = l15 & 7;

  __shared__ u16 arena[ARENA_ELEMS];   // 140.3 KB -> 1 block/CU (guarantees 32 blocks/XCD)
  __shared__ unsigned sslot;
  u16* lA0 = arena;
  u16* lA1 = arena + ATILE;
  u16* scr = arena + SCROFF;

  // ---- dynamic XCD roster: grouping correct by construction ----
  unsigned xcd;
  asm volatile("s_getreg_b32 %0, hwreg(HW_REG_XCC_ID)" : "=s"(xcd));
  if (tid == 0)
    sslot = __hip_atomic_fetch_add(&P.roster[xcd*32], 1u, __ATOMIC_RELAXED,
                                   __HIP_MEMORY_SCOPE_AGENT);
  __syncthreads();
  const int slot  = (int)(sslot & 31u);
  const int m_sub = slot & 3;          // 4-way m split within XCD
  const int n_sub = slot >> 2;         // 8-way n split within XCD
  const int m0   = (int)xcd*256 + m_sub*64;
  const int col0 = n_sub*64;           // this block's 64 hu columns
  const int hu   = col0 + wave*8 + hu7;

  unsigned* cnt = P.gcnt + xcd*32;     // per-XCD barrier line (32 arrivals)

  int aloff[4], boff[2];
  #pragma unroll
  for (int mf = 0; mf < 4; ++mf)
    aloff[mf] = (mf*16 + l15)*32 + quad*8;
  #pragma unroll
  for (int nf = 0; nf < 2; ++nf)
    boff[nf] = (n_sub*256 + wave*32 + nf*16 + l15)*HID + quad*8;

  float c0s[16], c1s[16];
  #pragma unroll
  for (int i = 0; i < 16; ++i){ c0s[i] = 0.f; c1s[i] = 0.f; }

  float be0v[4], be1v[4], bd0v[4], bd1v[4], wxev[4], wxdv[4];
  #pragma unroll
  for (int g = 0; g < 4; ++g){
    const int col = n_sub*256 + wave*32 + g*8 + hu7;
    be0v[g] = P.be0[col]; be1v[g] = P.be1[col];
    bd0v[g] = P.bd0[col]; bd1v[g] = P.bd1[col];
    wxev[g] = P.wxe[col]; wxdv[g] = P.wxd[col];
  }
  const float fcWv = P.fcW[hu];
  const float fcb  = P.fcbp[0];

  const size_t mb = (size_t)m0 * HID;
  u16* h0b[2] = { P.h0buf, P.h0buf + HBUF };
  u16* h1b[2] = { P.h1buf, P.h1buf + HBUF };

  unsigned epoch = 0;
  gbar(cnt, epoch);   // roster settled before anyone reads role-dependent h

  // ===== encoder: phase p runs layer0(t=p) and layer1(t=p-1) =====
  for (int p = 0; p <= S_LEN; ++p){
    stage_tile(h0b[p & 1] + mb,       lA0, wave, lane);
    stage_tile(h1b[(p+1) & 1] + mb,   lA1, wave, lane);
    __syncthreads();

    f32x4 acc0[4][2], acc1[4][2];
    #pragma unroll
    for (int i = 0; i < 4; ++i)
      #pragma unroll
      for (int j = 0; j < 2; ++j){ acc0[i][j] = f32x4{0.f,0.f,0.f,0.f}; acc1[i][j] = f32x4{0.f,0.f,0.f,0.f}; }

    gemm_lds<true >(lA0, P.We0,  P.We1i, acc0, acc1, aloff, boff);
    gemm_lds<false>(lA1, P.We1h, P.We1h, acc1, acc1, aloff, boff);

    if (p < S_LEN){
      float xin[16];
      #pragma unroll
      for (int mf = 0; mf < 4; ++mf)
        #pragma unroll
        for (int r = 0; r < 4; ++r)
          xin[mf*4+r] = P.x[(size_t)(m0 + mf*16 + quad*4 + r)*S_LEN + p];
      cell_epi<true,false>(acc0, c0s, be0v, wxev, xin, scr, wave, quad, l15, m0, 0.f, nullptr);
      drain_h(scr, h0b[(p+1) & 1], m0, col0, tid);
    }
    if (p >= 1){
      cell_epi<false,false>(acc1, c1s, be1v, nullptr, nullptr, scr, wave, quad, l15, m0, 0.f, nullptr);
      drain_h(scr, h1b[p & 1], m0, col0, tid);
    }
    gbar(cnt, epoch);
  }

  // ===== decoder: 2 phases per step (pred feedback) =====
  for (int t = 0; t < T_LEN; ++t){
    if (t > 0 && n_sub == 0 && tid < 64){
      const float pv = aloadf(&P.preds[((t+1) & 1)*BATCH + m0 + tid]);
      P.out[(size_t)(m0 + tid)*T_LEN + (t-1)] = pv + fcb;
    }
    { // phase A: dec layer0
      stage_tile(h0b[t & 1] + mb, lA0, wave, lane);
      __syncthreads();
      f32x4 acc0[4][2];
      #pragma unroll
      for (int i = 0; i < 4; ++i)
        #pragma unroll
        for (int j = 0; j < 2; ++j) acc0[i][j] = f32x4{0.f,0.f,0.f,0.f};
      gemm_lds<false>(lA0, P.Wd0, P.Wd0, acc0, acc0, aloff, boff);
      float xin[16];
      #pragma unroll
      for (int mf = 0; mf < 4; ++mf)
        #pragma unroll
        for (int r = 0; r < 4; ++r){
          const int b = m0 + mf*16 + quad*4 + r;
          xin[mf*4+r] = (t == 0) ? P.x[(size_t)b*S_LEN + (S_LEN-1)]
                                 : (aloadf(&P.preds[((t+1) & 1)*BATCH + b]) + fcb);
        }
      cell_epi<true,false>(acc0, c0s, bd0v, wxdv, xin, scr, wave, quad, l15, m0, 0.f, nullptr);
      drain_h(scr, h0b[(t+1) & 1], m0, col0, tid);
    }
    gbar(cnt, epoch);
    // phase B: dec layer1 + pred reduce
    if (n_sub == 0 && tid < 64)
      astoref(&P.preds[((t+1) & 1)*BATCH + m0 + tid], 0.f);   // recycle for step t+1
    {
      stage_tile(h0b[(t+1) & 1] + mb, lA0, wave, lane);
      stage_tile(h1b[t & 1] + mb,     lA1, wave, lane);
      __syncthreads();
      f32x4 acc1[4][2];
      #pragma unroll
      for (int i = 0; i < 4; ++i)
        #pragma unroll
        for (int j = 0; j < 2; ++j) acc1[i][j] = f32x4{0.f,0.f,0.f,0.f};
      gemm_lds<false>(lA0, P.Wd1i, P.Wd1i, acc1, acc1, aloff, boff);
      gemm_lds<false>(lA1, P.Wd1h, P.Wd1h, acc1, acc1, aloff, boff);
      cell_epi<false,true>(acc1, c1s, bd1v, nullptr, nullptr, scr, wave, quad, l15, m0,
                           fcWv, P.preds + (t & 1)*BATCH);
      drain_h(scr, h1b[(t+1) & 1], m0, col0, tid);
    }
    gbar(cnt, epoch);
  }
  if (n_sub == 0 && tid < 64){
    const float pv = aloadf(&P.preds[((T_LEN-1) & 1)*BATCH + m0 + tid]);
    P.out[(size_t)(m0 + tid)*T_LEN + (T_LEN-1)] = pv + fcb;
  }
}

// ---------------- host launcher ----------------
extern "C" void kernel_launch(void* const* d_in, const int* in_sizes, int n_in,
                              void* d_out, int out_size, void* d_ws, size_t ws_size,
                              hipStream_t stream){
  const float* x     = (const float*)d_in[0];
  const float* eWih0 = (const float*)d_in[1];
  const float* eWhh0 = (const float*)d_in[2];
  const float* ebih0 = (const float*)d_in[3];
  const float* ebhh0 = (const float*)d_in[4];
  const float* eWih1 = (const float*)d_in[5];
  const float* eWhh1 = (const float*)d_in[6];
  const float* ebih1 = (const float*)d_in[7];
  const float* ebhh1 = (const float*)d_in[8];
  const float* dWih0 = (const float*)d_in[9];
  const float* dWhh0 = (const float*)d_in[10];
  const float* dbih0 = (const float*)d_in[11];
  const float* dbhh0 = (const float*)d_in[12];
  const float* dWih1 = (const float*)d_in[13];
  const float* dWhh1 = (const float*)d_in[14];
  const float* dbih1 = (const float*)d_in[15];
  const float* dbhh1 = (const float*)d_in[16];
  const float* fcW   = (const float*)d_in[17];
  const float* fcb   = (const float*)d_in[18];

  char* ws = (char*)d_ws;
  size_t off = 0;
  auto alloc = [&](size_t bytes)->char*{
    char* p = ws + off; off += (bytes + 255) & ~(size_t)255; return p;
  };
  u16* We0  = (u16*)alloc((size_t)2048*512*2);
  u16* We1i = (u16*)alloc((size_t)2048*512*2);
  u16* We1h = (u16*)alloc((size_t)2048*512*2);
  u16* Wd0  = (u16*)alloc((size_t)2048*512*2);
  u16* Wd1i = (u16*)alloc((size_t)2048*512*2);
  u16* Wd1h = (u16*)alloc((size_t)2048*512*2);
  char* zbase = ws + off;
  u16* h0buf = (u16*)alloc(2*HBUF*2);
  u16* h1buf = (u16*)alloc(2*HBUF*2);
  float* preds = (float*)alloc(2*BATCH*4);
  unsigned* gcnt   = (unsigned*)alloc(8*32*4);   // per-XCD barrier lines
  unsigned* roster = (unsigned*)alloc(8*32*4);   // per-XCD slot claim lines
  size_t zbytes = (size_t)((ws + off) - zbase);
  float* be0 = (float*)alloc(2048*4);
  float* be1 = (float*)alloc(2048*4);
  float* bd0 = (float*)alloc(2048*4);
  float* bd1 = (float*)alloc(2048*4);
  float* wxe = (float*)alloc(2048*4);
  float* wxd = (float*)alloc(2048*4);

  hipMemsetAsync(zbase, 0, zbytes, stream);
  dim3 gw((2048*512)/256);
  k_reorder_w<<<gw,256,0,stream>>>(eWhh0, We0);
  k_reorder_w<<<gw,256,0,stream>>>(eWih1, We1i);
  k_reorder_w<<<gw,256,0,stream>>>(eWhh1, We1h);
  k_reorder_w<<<gw,256,0,stream>>>(dWhh0, Wd0);
  k_reorder_w<<<gw,256,0,stream>>>(dWih1, Wd1i);
  k_reorder_w<<<gw,256,0,stream>>>(dWhh1, Wd1h);
  k_prep_small<<<8,256,0,stream>>>(ebih0, ebhh0, be0, eWih0, wxe);
  k_prep_small<<<8,256,0,stream>>>(ebih1, ebhh1, be1, (const float*)nullptr, (float*)nullptr);
  k_prep_small<<<8,256,0,stream>>>(dbih0, dbhh0, bd0, dWih0, wxd);
  k_prep_small<<<8,256,0,stream>>>(dbih1, dbhh1, bd1, (const float*)nullptr, (float*)nullptr);

  Params P{ x, We0, We1i, We1h, Wd0, Wd1i, Wd1h,
            be0, be1, bd0, bd1, wxe, wxd, fcW, fcb,
            h0buf, h1buf, preds, gcnt, roster, (float*)d_out };
  // 256 blocks x 512 thr, 140KB LDS -> 1 block/CU -> exactly 32 blocks/XCD
  lstm_main<<<dim3(NBLK), dim3(THREADS), 0, stream>>>(P);
}

// Round 9
// 22667.532 us; speedup vs baseline: 1.4727x; 1.0096x over previous
//
#include <hip/hip_runtime.h>
#include <stdint.h>

typedef unsigned short u16;
typedef unsigned long long u64;
typedef __bf16 bf16x8 __attribute__((ext_vector_type(8)));
typedef float f32x4 __attribute__((ext_vector_type(4)));

#define S_LEN 288
#define T_LEN 144
#define HID   512
#define BATCH 2048
#define NBLK  256
#define THREADS 512
#define HBUF  ((size_t)BATCH * HID)

// LDS arena (u16 elems): two staged A tiles (chunk-major, 64B rows) + h scratch
#define ATILE  32768
#define SCROFF (2*ATILE)
#define ARENA_ELEMS (2*ATILE + 64*72)    // 140288 B -> 1 block/CU -> 32 blocks/XCD

#define MFMA16(a,b,c) __builtin_amdgcn_mfma_f32_16x16x32_bf16((a),(b),(c),0,0,0)

__device__ __forceinline__ u16 f2bf(float f){
  unsigned u = __builtin_bit_cast(unsigned, f);
  u = u + 0x7fffu + ((u >> 16) & 1u);
  return (u16)(u >> 16);
}
__device__ __forceinline__ float sigf(float x){ return 1.0f/(1.0f + __expf(-x)); }
__device__ __forceinline__ float tanh_f(float x){ return 1.0f - 2.0f/(1.0f + __expf(2.0f*x)); }

// agent-scope (sc1) — ONLY for barrier counters / roster / preds (tiny, cross-L2)
__device__ __forceinline__ float aloadf(const float* p){
  return __hip_atomic_load(p, __ATOMIC_RELAXED, __HIP_MEMORY_SCOPE_AGENT);
}
__device__ __forceinline__ void astoref(float* p, float v){
  __hip_atomic_store(p, v, __ATOMIC_RELAXED, __HIP_MEMORY_SCOPE_AGENT);
}

// async global->LDS, 16B/lane, aux=1 (sc0: bypass L1, read XCD-local L2)
__device__ __forceinline__ void glds16(const u16* g, u16* l){
  __builtin_amdgcn_global_load_lds(
      (const __attribute__((address_space(1))) void*)g,
      (__attribute__((address_space(3))) void*)l, 16, 0, 1);
}

struct Params {
  const float* x;
  const u16 *We0, *We1i, *We1h, *Wd0, *Wd1i, *Wd1h;
  const float *be0, *be1, *bd0, *bd1, *wxe, *wxd, *fcW, *fcbp;
  u16 *h0buf, *h1buf;
  float* preds;
  unsigned* gcnt;
  unsigned* roster;
  float* out;
};

// ---------------- prep kernels ----------------
// orig row = gate*512 + hu  ->  new row = (hu>>3)*32 + gate*8 + (hu&7)
__global__ void k_reorder_w(const float* __restrict__ src, u16* __restrict__ dst){
  int idx  = blockIdx.x * 256 + threadIdx.x;
  int k    = idx & (HID-1);
  int orig = idx >> 9;
  int gate = orig >> 9, hu = orig & (HID-1);
  int nr   = ((hu >> 3) << 5) + (gate << 3) + (hu & 7);
  dst[(size_t)nr * HID + k] = f2bf(src[idx]);
}

__global__ void k_prep_small(const float* __restrict__ bih, const float* __restrict__ bhh,
                             float* __restrict__ bdst,
                             const float* __restrict__ wcol, float* __restrict__ wdst){
  int orig = blockIdx.x * 256 + threadIdx.x;
  int gate = orig >> 9, hu = orig & (HID-1);
  int nr   = ((hu >> 3) << 5) + (gate << 3) + (hu & 7);
  bdst[nr] = bih[orig] + bhh[orig];
  if (wcol) wdst[nr] = wcol[orig];
}

// ---------------- per-XCD barrier (32 blocks), RELAXED (no wbl2) ----------------
// Safe because all inter-block h traffic is same-XCD through L2 (coherence point):
// each wave's s_waitcnt vmcnt(0) before s_barrier (inside the preceding
// __syncthreads) guarantees h stores are in L2 before tid0 bumps the counter.
__device__ __forceinline__ void gbar(unsigned* cnt, unsigned& epoch){
  __syncthreads();
  ++epoch;
  if (threadIdx.x == 0){
    __hip_atomic_fetch_add(cnt, 1u, __ATOMIC_RELAXED, __HIP_MEMORY_SCOPE_AGENT);
    const unsigned tgt = epoch * 32u;
    while (__hip_atomic_load(cnt, __ATOMIC_RELAXED, __HIP_MEMORY_SCOPE_AGENT) < tgt)
      __builtin_amdgcn_s_sleep(1);
  }
  __syncthreads();
}

// ---------------- A-tile staging (sc0 -> XCD L2), source-swizzled ----------------
// LDS: chunk c at c*2048 elems, row r at r*32 (64B rows, lane-contiguous - no pad).
// Source col is XOR-permuted so fragment reads are <=2-way bank aliased:
// lane: r_in=lane>>2, qq=lane&3 reads global 16B-slot qq ^ ((r_in>>2)&3).
__device__ __forceinline__ void stage_tile(const u16* __restrict__ Ag, u16* lA,
                                           int wave, int lane){
  const int r_in = lane >> 2, qq = lane & 3;
  const int qg = qq ^ ((r_in >> 2) & 3);
  #pragma unroll
  for (int j = 0; j < 8; ++j){
    const int idx = wave*8 + j;
    const int c = idx >> 2, rq = idx & 3;
    const u16* g = Ag + (size_t)(rq*16 + r_in)*HID + c*32 + qg*8;
    glds16(g, lA + c*2048 + rq*512);
  }
}

// ---------------- fused encoder K-loop: 2 A-tiles x 3 B-streams, depth-4 --------
__device__ __forceinline__ void gemm_enc(
    const u16* lA0, const u16* lA1,
    const u16* __restrict__ B0, const u16* __restrict__ B1, const u16* __restrict__ B2,
    f32x4 (&acc0)[4][2], f32x4 (&acc1)[4][2],
    const int (&aloff)[4], const int (&boff)[2])
{
  int4 q0[4][2], q1[4][2], q2[4][2];
  #pragma unroll
  for (int st = 0; st < 4; ++st)
    #pragma unroll
    for (int nf = 0; nf < 2; ++nf){
      q0[st][nf] = *(const int4*)(B0 + boff[nf] + st*32);
      q1[st][nf] = *(const int4*)(B1 + boff[nf] + st*32);
      q2[st][nf] = *(const int4*)(B2 + boff[nf] + st*32);
    }
  __syncthreads();   // glds16 staging + primes drained
  #pragma unroll
  for (int c = 0; c < 16; ++c){
    bf16x8 a0[4], a1[4];
    #pragma unroll
    for (int mf = 0; mf < 4; ++mf){
      a0[mf] = *(const bf16x8*)&lA0[c*2048 + aloff[mf]];
      a1[mf] = *(const bf16x8*)&lA1[c*2048 + aloff[mf]];
    }
    const int st = c & 3;
    #pragma unroll
    for (int mf = 0; mf < 4; ++mf)
      #pragma unroll
      for (int nf = 0; nf < 2; ++nf){
        acc0[mf][nf] = MFMA16(a0[mf], __builtin_bit_cast(bf16x8, q0[st][nf]), acc0[mf][nf]);
        acc1[mf][nf] = MFMA16(a0[mf], __builtin_bit_cast(bf16x8, q1[st][nf]), acc1[mf][nf]);
        acc1[mf][nf] = MFMA16(a1[mf], __builtin_bit_cast(bf16x8, q2[st][nf]), acc1[mf][nf]);
      }
    if (c < 12){
      #pragma unroll
      for (int nf = 0; nf < 2; ++nf){
        q0[st][nf] = *(const int4*)(B0 + boff[nf] + (c+4)*32);
        q1[st][nf] = *(const int4*)(B1 + boff[nf] + (c+4)*32);
        q2[st][nf] = *(const int4*)(B2 + boff[nf] + (c+4)*32);
      }
    }
  }
}

// ---------------- decoder phase A: 1 A-tile x 1 B-stream, depth-8 ----------------
__device__ __forceinline__ void gemm_dec1(
    const u16* lA0, const u16* __restrict__ B0,
    f32x4 (&acc)[4][2], const int (&aloff)[4], const int (&boff)[2])
{
  int4 q[8][2];
  #pragma unroll
  for (int st = 0; st < 8; ++st)
    #pragma unroll
    for (int nf = 0; nf < 2; ++nf)
      q[st][nf] = *(const int4*)(B0 + boff[nf] + st*32);
  __syncthreads();
  #pragma unroll
  for (int c = 0; c < 16; ++c){
    bf16x8 a0[4];
    #pragma unroll
    for (int mf = 0; mf < 4; ++mf)
      a0[mf] = *(const bf16x8*)&lA0[c*2048 + aloff[mf]];
    const int st = c & 7;
    #pragma unroll
    for (int mf = 0; mf < 4; ++mf)
      #pragma unroll
      for (int nf = 0; nf < 2; ++nf)
        acc[mf][nf] = MFMA16(a0[mf], __builtin_bit_cast(bf16x8, q[st][nf]), acc[mf][nf]);
    if (c < 8){
      #pragma unroll
      for (int nf = 0; nf < 2; ++nf)
        q[st][nf] = *(const int4*)(B0 + boff[nf] + (c+8)*32);
    }
  }
}

// ---------------- decoder phase B: 2 A-tiles x 2 B-streams, depth-5 --------------
__device__ __forceinline__ void gemm_dec2(
    const u16* lA0, const u16* lA1,
    const u16* __restrict__ B1, const u16* __restrict__ B2,
    f32x4 (&acc)[4][2], const int (&aloff)[4], const int (&boff)[2])
{
  int4 q1[5][2], q2[5][2];
  #pragma unroll
  for (int st = 0; st < 5; ++st)
    #pragma unroll
    for (int nf = 0; nf < 2; ++nf){
      q1[st][nf] = *(const int4*)(B1 + boff[nf] + st*32);
      q2[st][nf] = *(const int4*)(B2 + boff[nf] + st*32);
    }
  __syncthreads();
  #pragma unroll
  for (int c = 0; c < 16; ++c){
    bf16x8 a0[4], a1[4];
    #pragma unroll
    for (int mf = 0; mf < 4; ++mf){
      a0[mf] = *(const bf16x8*)&lA0[c*2048 + aloff[mf]];
      a1[mf] = *(const bf16x8*)&lA1[c*2048 + aloff[mf]];
    }
    const int st = c % 5;
    #pragma unroll
    for (int mf = 0; mf < 4; ++mf)
      #pragma unroll
      for (int nf = 0; nf < 2; ++nf){
        acc[mf][nf] = MFMA16(a0[mf], __builtin_bit_cast(bf16x8, q1[st][nf]), acc[mf][nf]);
        acc[mf][nf] = MFMA16(a1[mf], __builtin_bit_cast(bf16x8, q2[st][nf]), acc[mf][nf]);
      }
    if (c < 11){
      #pragma unroll
      for (int nf = 0; nf < 2; ++nf){
        q1[st][nf] = *(const int4*)(B1 + boff[nf] + (c+5)*32);
        q2[st][nf] = *(const int4*)(B2 + boff[nf] + (c+5)*32);
      }
    }
  }
}

// ---------------- LSTM cell epilogue (R4/R5-proven gate mapping) ----------------
template<bool X0, bool PRED>
__device__ __forceinline__ void cell_epi(
    f32x4 (&acc)[4][2], float* cst, const float* bv, const float* wxv,
    const float* xin, u16* scr,
    int wave, int quad, int l15, int m0,
    float fcWv, float* predrow)
{
  const int hilane = l15 >> 3, hu7 = l15 & 7;
  #pragma unroll
  for (int mf = 0; mf < 4; ++mf){
    #pragma unroll
    for (int r = 0; r < 4; ++r){
      const float a0 = acc[mf][0][r], a1 = acc[mf][1][r];
      const float p0 = __shfl_xor(a0, 8), p1 = __shfl_xor(a1, 8);
      float gi = (hilane ? p0 : a0) + bv[0];
      float gf = (hilane ? a0 : p0) + bv[1];
      float gg = (hilane ? p1 : a1) + bv[2];
      float go = (hilane ? a1 : p1) + bv[3];
      if (X0){
        const float xt = xin[mf*4 + r];
        gi += xt*wxv[0]; gf += xt*wxv[1]; gg += xt*wxv[2]; go += xt*wxv[3];
      }
      const float c = sigf(gf)*cst[mf*4+r] + sigf(gi)*tanh_f(gg);
      cst[mf*4+r] = c;
      const float h = sigf(go)*tanh_f(c);
      if (!hilane) scr[(mf*16 + quad*4 + r)*72 + wave*8 + hu7] = f2bf(h);
      if (PRED){
        float v = hilane ? 0.f : h*fcWv;
        v += __shfl_xor(v, 1); v += __shfl_xor(v, 2);
        v += __shfl_xor(v, 4); v += __shfl_xor(v, 8);
        if (l15 == 0) atomicAdd(&predrow[m0 + mf*16 + quad*4 + r], v);
      }
    }
  }
}

// drain scratch (64 rows x 64 cols, pitch 72) -> global h (plain stores -> XCD L2)
__device__ __forceinline__ void drain_h(const u16* scr, u16* hdst, int m0, int col0, int tid){
  __syncthreads();
  const int row = tid >> 3, q = tid & 7;
  const int4 v = *(const int4*)(scr + row*72 + q*8);
  *(int4*)(hdst + (size_t)(m0+row)*HID + col0 + q*8) = v;
  __syncthreads();
}

// ---------------- persistent main kernel ----------------
__global__ __launch_bounds__(THREADS, 1) void lstm_main(Params P){
  const int tid = threadIdx.x;
  const int wave = tid >> 6, lane = tid & 63;
  const int l15 = lane & 15, quad = lane >> 4;
  const int hu7 = l15 & 7;

  __shared__ u16 arena[ARENA_ELEMS];   // 140.3 KB -> 1 block/CU -> 32 blocks/XCD
  __shared__ unsigned sslot;
  u16* lA0 = arena;
  u16* lA1 = arena + ATILE;
  u16* scr = arena + SCROFF;

  // ---- dynamic XCD roster ----
  unsigned xcd;
  asm volatile("s_getreg_b32 %0, hwreg(HW_REG_XCC_ID)" : "=s"(xcd));
  if (tid == 0)
    sslot = __hip_atomic_fetch_add(&P.roster[xcd*32], 1u, __ATOMIC_RELAXED,
                                   __HIP_MEMORY_SCOPE_AGENT);
  __syncthreads();
  const int slot  = (int)(sslot & 31u);
  const int m_sub = slot & 3;
  const int n_sub = slot >> 2;
  const int m0   = (int)xcd*256 + m_sub*64;
  const int col0 = n_sub*64;
  const int hu   = col0 + wave*8 + hu7;

  unsigned* cnt = P.gcnt + xcd*32;

  // fragment offsets: read slot = quad ^ swz(l15) (matches staging source permute)
  const int swz = (l15 >> 2) & 3;
  int aloff[4], boff[2];
  #pragma unroll
  for (int mf = 0; mf < 4; ++mf)
    aloff[mf] = (mf*16 + l15)*32 + ((quad ^ swz) << 3);
  #pragma unroll
  for (int nf = 0; nf < 2; ++nf)
    boff[nf] = (n_sub*256 + wave*32 + nf*16 + l15)*HID + quad*8;

  float c0s[16], c1s[16];
  #pragma unroll
  for (int i = 0; i < 16; ++i){ c0s[i] = 0.f; c1s[i] = 0.f; }

  float be0v[4], be1v[4], bd0v[4], bd1v[4], wxev[4], wxdv[4];
  #pragma unroll
  for (int g = 0; g < 4; ++g){
    const int col = n_sub*256 + wave*32 + g*8 + hu7;
    be0v[g] = P.be0[col]; be1v[g] = P.be1[col];
    bd0v[g] = P.bd0[col]; bd1v[g] = P.bd1[col];
    wxev[g] = P.wxe[col]; wxdv[g] = P.wxd[col];
  }
  const float fcWv = P.fcW[hu];
  const float fcb  = P.fcbp[0];

  const size_t mb = (size_t)m0 * HID;
  u16* h0b[2] = { P.h0buf, P.h0buf + HBUF };
  u16* h1b[2] = { P.h1buf, P.h1buf + HBUF };

  unsigned epoch = 0;
  gbar(cnt, epoch);   // roster settled

  // ===== encoder: phase p runs layer0(t=p) and layer1(t=p-1) =====
  for (int p = 0; p <= S_LEN; ++p){
    stage_tile(h0b[p & 1] + mb,     lA0, wave, lane);
    stage_tile(h1b[(p+1) & 1] + mb, lA1, wave, lane);

    float xin[16];
    if (p < S_LEN){
      #pragma unroll
      for (int mf = 0; mf < 4; ++mf)
        #pragma unroll
        for (int r = 0; r < 4; ++r)
          xin[mf*4+r] = P.x[(size_t)(m0 + mf*16 + quad*4 + r)*S_LEN + p];
    }

    f32x4 acc0[4][2], acc1[4][2];
    #pragma unroll
    for (int i = 0; i < 4; ++i)
      #pragma unroll
      for (int j = 0; j < 2; ++j){ acc0[i][j] = f32x4{0.f,0.f,0.f,0.f}; acc1[i][j] = f32x4{0.f,0.f,0.f,0.f}; }

    gemm_enc(lA0, lA1, P.We0, P.We1i, P.We1h, acc0, acc1, aloff, boff);

    if (p < S_LEN){
      cell_epi<true,false>(acc0, c0s, be0v, wxev, xin, scr, wave, quad, l15, m0, 0.f, nullptr);
      drain_h(scr, h0b[(p+1) & 1], m0, col0, tid);
    }
    if (p >= 1){
      cell_epi<false,false>(acc1, c1s, be1v, nullptr, nullptr, scr, wave, quad, l15, m0, 0.f, nullptr);
      drain_h(scr, h1b[p & 1], m0, col0, tid);
    }
    gbar(cnt, epoch);
  }

  // ===== decoder: 2 phases per step (pred feedback) =====
  for (int t = 0; t < T_LEN; ++t){
    if (t > 0 && n_sub == 0 && tid < 64){
      const float pv = aloadf(&P.preds[((t+1) & 1)*BATCH + m0 + tid]);
      P.out[(size_t)(m0 + tid)*T_LEN + (t-1)] = pv + fcb;
    }
    { // phase A: dec layer0
      stage_tile(h0b[t & 1] + mb, lA0, wave, lane);
      float xin[16];
      #pragma unroll
      for (int mf = 0; mf < 4; ++mf)
        #pragma unroll
        for (int r = 0; r < 4; ++r){
          const int b = m0 + mf*16 + quad*4 + r;
          xin[mf*4+r] = (t == 0) ? P.x[(size_t)b*S_LEN + (S_LEN-1)]
                                 : (aloadf(&P.preds[((t+1) & 1)*BATCH + b]) + fcb);
        }
      f32x4 acc0[4][2];
      #pragma unroll
      for (int i = 0; i < 4; ++i)
        #pragma unroll
        for (int j = 0; j < 2; ++j) acc0[i][j] = f32x4{0.f,0.f,0.f,0.f};
      gemm_dec1(lA0, P.Wd0, acc0, aloff, boff);
      cell_epi<true,false>(acc0, c0s, bd0v, wxdv, xin, scr, wave, quad, l15, m0, 0.f, nullptr);
      drain_h(scr, h0b[(t+1) & 1], m0, col0, tid);
    }
    gbar(cnt, epoch);
    // phase B: dec layer1 + pred reduce
    if (n_sub == 0 && tid < 64)
      astoref(&P.preds[((t+1) & 1)*BATCH + m0 + tid], 0.f);
    {
      stage_tile(h0b[(t+1) & 1] + mb, lA0, wave, lane);
      stage_tile(h1b[t & 1] + mb,     lA1, wave, lane);
      f32x4 acc1[4][2];
      #pragma unroll
      for (int i = 0; i < 4; ++i)
        #pragma unroll
        for (int j = 0; j < 2; ++j) acc1[i][j] = f32x4{0.f,0.f,0.f,0.f};
      gemm_dec2(lA0, lA1, P.Wd1i, P.Wd1h, acc1, aloff, boff);
      cell_epi<false,true>(acc1, c1s, bd1v, nullptr, nullptr, scr, wave, quad, l15, m0,
                           fcWv, P.preds + (t & 1)*BATCH);
      drain_h(scr, h1b[(t+1) & 1], m0, col0, tid);
    }
    gbar(cnt, epoch);
  }
  if (n_sub == 0 && tid < 64){
    const float pv = aloadf(&P.preds[((T_LEN-1) & 1)*BATCH + m0 + tid]);
    P.out[(size_t)(m0 + tid)*T_LEN + (T_LEN-1)] = pv + fcb;
  }
}

// ---------------- host launcher ----------------
extern "C" void kernel_launch(void* const* d_in, const int* in_sizes, int n_in,
                              void* d_out, int out_size, void* d_ws, size_t ws_size,
                              hipStream_t stream){
  const float* x     = (const float*)d_in[0];
  const float* eWih0 = (const float*)d_in[1];
  const float* eWhh0 = (const float*)d_in[2];
  const float* ebih0 = (const float*)d_in[3];
  const float* ebhh0 = (const float*)d_in[4];
  const float* eWih1 = (const float*)d_in[5];
  const float* eWhh1 = (const float*)d_in[6];
  const float* ebih1 = (const float*)d_in[7];
  const float* ebhh1 = (const float*)d_in[8];
  const float* dWih0 = (const float*)d_in[9];
  const float* dWhh0 = (const float*)d_in[10];
  const float* dbih0 = (const float*)d_in[11];
  const float* dbhh0 = (const float*)d_in[12];
  const float* dWih1 = (const float*)d_in[13];
  const float* dWhh1 = (const float*)d_in[14];
  const float* dbih1 = (const float*)d_in[15];
  const float* dbhh1 = (const float*)d_in[16];
  const float* fcW   = (const float*)d_in[17];
  const float* fcb   = (const float*)d_in[18];

  char* ws = (char*)d_ws;
  size_t off = 0;
  auto alloc = [&](size_t bytes)->char*{
    char* p = ws + off; off += (bytes + 255) & ~(size_t)255; return p;
  };
  u16* We0  = (u16*)alloc((size_t)2048*512*2);
  u16* We1i = (u16*)alloc((size_t)2048*512*2);
  u16* We1h = (u16*)alloc((size_t)2048*512*2);
  u16* Wd0  = (u16*)alloc((size_t)2048*512*2);
  u16* Wd1i = (u16*)alloc((size_t)2048*512*2);
  u16* Wd1h = (u16*)alloc((size_t)2048*512*2);
  char* zbase = ws + off;
  u16* h0buf = (u16*)alloc(2*HBUF*2);
  u16* h1buf = (u16*)alloc(2*HBUF*2);
  float* preds = (float*)alloc(2*BATCH*4);
  unsigned* gcnt   = (unsigned*)alloc(8*32*4);
  unsigned* roster = (unsigned*)alloc(8*32*4);
  size_t zbytes = (size_t)((ws + off) - zbase);
  float* be0 = (float*)alloc(2048*4);
  float* be1 = (float*)alloc(2048*4);
  float* bd0 = (float*)alloc(2048*4);
  float* bd1 = (float*)alloc(2048*4);
  float* wxe = (float*)alloc(2048*4);
  float* wxd = (float*)alloc(2048*4);

  hipMemsetAsync(zbase, 0, zbytes, stream);
  dim3 gw((2048*512)/256);
  k_reorder_w<<<gw,256,0,stream>>>(eWhh0, We0);
  k_reorder_w<<<gw,256,0,stream>>>(eWih1, We1i);
  k_reorder_w<<<gw,256,0,stream>>>(eWhh1, We1h);
  k_reorder_w<<<gw,256,0,stream>>>(dWhh0, Wd0);
  k_reorder_w<<<gw,256,0,stream>>>(dWih1, Wd1i);
  k_reorder_w<<<gw,256,0,stream>>>(dWhh1, Wd1h);
  k_prep_small<<<8,256,0,stream>>>(ebih0, ebhh0, be0, eWih0, wxe);
  k_prep_small<<<8,256,0,stream>>>(ebih1, ebhh1, be1, (const float*)nullptr, (float*)nullptr);
  k_prep_small<<<8,256,0,stream>>>(dbih0, dbhh0, bd0, dWih0, wxd);
  k_prep_small<<<8,256,0,stream>>>(dbih1, dbhh1, bd1, (const float*)nullptr, (float*)nullptr);

  Params P{ x, We0, We1i, We1h, Wd0, Wd1i, Wd1h,
            be0, be1, bd0, bd1, wxe, wxd, fcW, fcb,
            h0buf, h1buf, preds, gcnt, roster, (float*)d_out };
  lstm_main<<<dim3(NBLK), dim3(THREADS), 0, stream>>>(P);
}